// Round 11
// baseline (1156.539 us; speedup 1.0000x reference)
//
#include <hip/hip_runtime.h>
#include <math.h>

// Problem constants (from reference): x[B][L][D] fp32
#define B 8
#define L 4096
#define D 512
#define LC 64               // chunk length
#define CK (L / LC)         // 64 chunks
#define BLD ((size_t)B * L * D)

#define NCHAIN (B * 2)               // (b, d-half) chains
#define NBLK (NCHAIN * CK)           // 1024 blocks = 4 blocks/CU exactly

// ws layout: aggV [NBLK][256][2] floats (2 MiB), then flags[NBLK] uint (4 KiB)
#define AGG_FLOATS ((size_t)NBLK * 256 * 2)
#define FLAG_BYTE_OFF (AGG_FLOATS * sizeof(float))
#define WS_NEED (FLAG_BYTE_OFF + (size_t)NBLK * sizeof(unsigned int))

typedef float v2f __attribute__((ext_vector_type(2)));

// phazor = exp(-|z|^2) * z/|z|   (no trig needed)
__device__ __forceinline__ v2f phazor_of(const float* __restrict__ pparam, int d) {
    float a = pparam[d * 2 + 0];
    float bb = pparam[d * 2 + 1];
    float r2 = fmaf(a, a, bb * bb);
    float inv = rsqrtf(r2);
    inv = inv * fmaf(-0.5f * r2 * inv, inv, 1.5f);   // Newton refinement
    float mag = __expf(-r2);
    v2f p; p.x = mag * a * inv; p.y = mag * bb * inv;
    return p;
}

// P64 = phazor^LC via 6 complex squarings
__device__ __forceinline__ v2f p64_of(v2f ph) {
    float br = ph.x, bi = ph.y;
#pragma unroll
    for (int s = 0; s < 6; ++s) {
        float sr = fmaf(br, br, -bi * bi);
        float si = 2.f * br * bi;
        br = sr; bi = si;
    }
    v2f r; r.x = br; r.y = bi;
    return r;
}

// Single-pass decoupled-lookback scan.
// Block g: c = g % CK (chunk), chain = g / CK, b = chain>>1, d = (chain&1)*256 + tid.
// MODE 0: out = [real plane][real plane];  MODE 1: [real][interleaved re,im]
template <int MODE>
__global__ __launch_bounds__(256) void scan_k(const float* __restrict__ x,
                                              const float* __restrict__ hr,
                                              const float* __restrict__ hi,
                                              const float* __restrict__ pinit,
                                              const float* __restrict__ pparam,
                                              float* __restrict__ aggv,
                                              unsigned int* __restrict__ flags,
                                              float* __restrict__ out) {
    int g = blockIdx.x;
    int c = g % CK;                      // block-uniform
    int chain = g / CK;
    int b = chain >> 1;
    int d = (chain & 1) * 256 + threadIdx.x;

    v2f ph = phazor_of(pparam, d);
    v2f P = p64_of(ph);

    // ---- phase 1: chunk-local scan (zero carry-in) ----
    const float* xp = x + ((size_t)b * L + (size_t)c * LC) * D + d;
    float ar = 0.f, ai = 0.f;
#pragma unroll 8
    for (int i = 0; i < LC; ++i) {
        float xv = xp[(size_t)i * D];
        float nr = fmaf(ph.x, ar, fmaf(-ph.y, ai, xv));
        float ni = fmaf(ph.x, ai, ph.y * ar);
        ar = nr; ai = ni;
    }

    // ---- publish aggregate (last chunk of each chain is never read) ----
    if (c != CK - 1) {
        v2f av; av.x = ar; av.y = ai;
        *(v2f*)(aggv + ((size_t)g * 256 + threadIdx.x) * 2) = av;
        __threadfence();
        __syncthreads();
        if (threadIdx.x == 0)
            __hip_atomic_store(&flags[g], 1u, __ATOMIC_RELEASE, __HIP_MEMORY_SCOPE_AGENT);
    }

    // ---- lookback: W = sum_{j<c} P64^{c-1-j} * A_j  (ascending Horner) ----
    float wr = 0.f, wi = 0.f;
    int base = chain * CK;
    for (int j = 0; j < c; ++j) {
        while (__hip_atomic_load(&flags[base + j], __ATOMIC_ACQUIRE,
                                 __HIP_MEMORY_SCOPE_AGENT) == 0u) {
            __builtin_amdgcn_s_sleep(1);
        }
        v2f av = *(const v2f*)(aggv + ((size_t)(base + j) * 256 + threadIdx.x) * 2);
        float tr = fmaf(wr, P.x, fmaf(-wi, P.y, av.x));
        float ti = fmaf(wr, P.y, fmaf(wi, P.x, av.y));
        wr = tr; wi = ti;
    }

    // ---- pw = phazor^(c*LC + 1) = P64^c * phazor  (binary exp, 6 bits) ----
    float pwr = ph.x, pwi = ph.y;
    {
        float er = P.x, ei = P.y;
        int n = c;
#pragma unroll
        for (int s = 0; s < 6; ++s) {
            if (n & 1) {
                float tr = fmaf(pwr, er, -pwi * ei);
                float ti = fmaf(pwr, ei, pwi * er);
                pwr = tr; pwi = ti;
            }
            float sr = fmaf(er, er, -ei * ei);
            float si = 2.f * er * ei;
            er = sr; ei = si;
            n >>= 1;
        }
    }

    float hre = hr[(size_t)b * D + d];
    float him = hi[(size_t)b * D + d];
    v2f q; q.x = pinit[d * 2 + 0]; q.y = pinit[d * 2 + 1];

    // ---- phase 2: re-scan chunk with carry, write outputs (x is cache-hot) ----
    float* outr = out + ((size_t)b * L + (size_t)c * LC) * D + d;
    float* outr2 = outr + BLD;
    float* outc = out + BLD + (((size_t)b * L + (size_t)c * LC) * D + d) * 2;

    float ur = wr, ui = wi;
#pragma unroll 4
    for (int i = 0; i < LC; ++i) {
        float xv = xp[(size_t)i * D];
        float nr = fmaf(ph.x, ur, fmaf(-ph.y, ui, xv));
        float ni = fmaf(ph.x, ui, ph.y * ur);
        ur = nr; ui = ni;
        float vr = fmaf(q.x, ur, fmaf(-q.y, ui, fmaf(hre, pwr, -him * pwi)));
        float vi = fmaf(q.x, ui, fmaf(q.y, ur, fmaf(hre, pwi, him * pwr)));
        outr[(size_t)i * D] = vr;
        if (MODE == 0) {
            outr2[(size_t)i * D] = vr;
        } else {
            v2f vc; vc.x = vr; vc.y = vi;
            *(v2f*)(outc + (size_t)i * D * 2) = vc;
        }
        float tr = fmaf(pwr, ph.x, -pwi * ph.y);
        float ti = fmaf(pwr, ph.y, pwi * ph.x);
        pwr = tr; pwi = ti;
    }
}

// Serial fallback (no scratch): one thread per (b,d), full-L scan.
template <int MODE>
__global__ __launch_bounds__(256) void fallback_k(const float* __restrict__ x,
                                                  const float* __restrict__ hr,
                                                  const float* __restrict__ hi,
                                                  const float* __restrict__ pinit,
                                                  const float* __restrict__ pparam,
                                                  float* __restrict__ out) {
    int idx = blockIdx.x * blockDim.x + threadIdx.x;
    if (idx >= B * D) return;
    int d = idx % D;
    int b = idx / D;
    v2f ph = phazor_of(pparam, d);
    float qr = pinit[d * 2 + 0];
    float qi = pinit[d * 2 + 1];
    float hre = hr[(size_t)b * D + d];
    float him = hi[(size_t)b * D + d];
    float ur = 0.f, ui = 0.f;
    float pwr = ph.x, pwi = ph.y;
    const float* xp = x + (size_t)b * L * D + d;
    float* outr = out + (size_t)b * L * D + d;
    float* outr2 = outr + BLD;
    float* outc = out + BLD + ((size_t)b * L * D + d) * 2;
    for (int t = 0; t < L; ++t) {
        float xv = xp[(size_t)t * D];
        float nr = fmaf(ph.x, ur, fmaf(-ph.y, ui, xv));
        float ni = fmaf(ph.x, ui, ph.y * ur);
        ur = nr; ui = ni;
        float vr = fmaf(qr, ur, fmaf(-qi, ui, fmaf(hre, pwr, -him * pwi)));
        float vi = fmaf(qr, ui, fmaf(qi, ur, fmaf(hre, pwi, him * pwr)));
        outr[(size_t)t * D] = vr;
        if (MODE == 0) {
            outr2[(size_t)t * D] = vr;
        } else {
            v2f vc; vc.x = vr; vc.y = vi;
            *(v2f*)(outc + (size_t)t * D * 2) = vc;
        }
        float tr = fmaf(pwr, ph.x, -pwi * ph.y);
        float ti = fmaf(pwr, ph.y, pwi * ph.x);
        pwr = tr; pwi = ti;
    }
}

extern "C" void kernel_launch(void* const* d_in, const int* in_sizes, int n_in,
                              void* d_out, int out_size, void* d_ws, size_t ws_size,
                              hipStream_t stream) {
    const float* x = (const float*)d_in[0];
    const float* hreal = (const float*)d_in[1];
    const float* himag = (const float*)d_in[2];
    const float* pinit = (const float*)d_in[3];
    const float* pparam = (const float*)d_in[4];
    float* out = (float*)d_out;

    const int mode = (out_size >= (int)(3 * BLD)) ? 1 : 0;

    if (ws_size >= WS_NEED) {
        float* aggv = (float*)d_ws;
        unsigned int* flags = (unsigned int*)((char*)d_ws + FLAG_BYTE_OFF);
        hipMemsetAsync((void*)flags, 0, NBLK * sizeof(unsigned int), stream);
        if (mode == 0)
            scan_k<0><<<NBLK, 256, 0, stream>>>(x, hreal, himag, pinit, pparam, aggv, flags, out);
        else
            scan_k<1><<<NBLK, 256, 0, stream>>>(x, hreal, himag, pinit, pparam, aggv, flags, out);
    } else {
        int n = B * D;
        if (mode == 0)
            fallback_k<0><<<(n + 255) / 256, 256, 0, stream>>>(x, hreal, himag, pinit, pparam, out);
        else
            fallback_k<1><<<(n + 255) / 256, 256, 0, stream>>>(x, hreal, himag, pinit, pparam, out);
    }
}

// Round 12
// 52.108 us; speedup vs baseline: 22.1951x; 22.1951x over previous
//
#include <hip/hip_runtime.h>
#include <math.h>

// Problem constants (from reference): x[B][L][D] fp32
#define B 8
#define L 4096
#define D 512
#define LC 64               // chunk length
#define CK (L / LC)         // 64 chunks
#define BLD ((size_t)B * L * D)

typedef float v2f __attribute__((ext_vector_type(2)));

// ws layout (floats): le [B][CK][D][2]  (chunk-local scan end states)
#define WS_FLOATS (2 * B * CK * D)           // 2 MiB

// phazor = exp(-|z|^2) * z/|z|   (no trig needed)
__device__ __forceinline__ v2f phazor_of(const float* __restrict__ pparam, int d) {
    float a = pparam[d * 2 + 0];
    float bb = pparam[d * 2 + 1];
    float r2 = fmaf(a, a, bb * bb);
    float inv = rsqrtf(r2);
    inv = inv * fmaf(-0.5f * r2 * inv, inv, 1.5f);   // Newton refinement
    float mag = __expf(-r2);
    v2f p; p.x = mag * a * inv; p.y = mag * bb * inv;
    return p;
}

// Pass 1: chunk-local scan with zero carry-in; store final state per (b,c,d).
__global__ __launch_bounds__(256) void pass1_k(const float* __restrict__ x,
                                               const float* __restrict__ pparam,
                                               float* __restrict__ le) {
    int idx = blockIdx.x * blockDim.x + threadIdx.x;   // b*CK*D + c*D + d
    int d = idx % D;
    int c = (idx / D) % CK;
    int b = idx / (D * CK);
    v2f ph = phazor_of(pparam, d);
    float ur = 0.f, ui = 0.f;
    const float* xp = x + ((size_t)b * L + (size_t)c * LC) * D + d;
#pragma unroll 8
    for (int i = 0; i < LC; ++i) {
        float xv = xp[(size_t)i * D];
        float nr = fmaf(ph.x, ur, fmaf(-ph.y, ui, xv));
        float ni = fmaf(ph.x, ui, ph.y * ur);
        ur = nr;
        ui = ni;
    }
    v2f lv; lv.x = ur; lv.y = ui;
    *(v2f*)(le + (size_t)idx * 2) = lv;
}

// Pass 2: rebuild carry-in by Horner over previous chunk ends (only needs
// P64 = phazor^LC), re-scan the chunk, write outputs nontemporally.
// MODE 0: out = [real plane][real plane]   (harness cast complex64 -> float32)
// MODE 1: out = [real plane][interleaved (re,im) plane]
template <int MODE>
__global__ __launch_bounds__(256) void pass2_k(const float* __restrict__ x,
                                               const float* __restrict__ hr,
                                               const float* __restrict__ hi,
                                               const float* __restrict__ pinit,
                                               const float* __restrict__ pparam,
                                               const float* __restrict__ le,
                                               float* __restrict__ out) {
    int idx = blockIdx.x * blockDim.x + threadIdx.x;   // b*CK*D + c*D + d
    int d = idx % D;
    int c = (idx / D) % CK;       // uniform within a block
    int b = idx / (D * CK);

    v2f ph = phazor_of(pparam, d);
    v2f q;  q.x = pinit[d * 2 + 0]; q.y = pinit[d * 2 + 1];

    // P64 = phazor^LC via 6 complex squarings
    float br = ph.x, bi = ph.y;
#pragma unroll
    for (int s = 0; s < 6; ++s) {
        float sr = fmaf(br, br, -bi * bi);
        float si = 2.f * br * bi;
        br = sr; bi = si;
    }

    // carry-in W[c] = sum_{j<c} P64^{c-1-j} * le[b][j][d]  (Horner, ascending j)
    float ur = 0.f, ui = 0.f;
    const float* lp = le + (((size_t)b * CK) * D + d) * 2;
    for (int j = 0; j < c; ++j) {
        v2f lv = *(const v2f*)(lp + (size_t)j * D * 2);
        float wr = fmaf(ur, br, fmaf(-ui, bi, lv.x));
        float wi = fmaf(ur, bi, fmaf(ui, br, lv.y));
        ur = wr; ui = wi;
    }

    // pw = phazor^(c*LC + 1) = P64^c * phazor  (binary exp over 6 bits of c)
    float pwr = ph.x, pwi = ph.y;
    {
        float er = br, ei = bi;
        int n = c;
#pragma unroll
        for (int s = 0; s < 6; ++s) {
            if (n & 1) {
                float tr = fmaf(pwr, er, -pwi * ei);
                float ti = fmaf(pwr, ei, pwi * er);
                pwr = tr; pwi = ti;
            }
            float sr = fmaf(er, er, -ei * ei);
            float si = 2.f * er * ei;
            er = sr; ei = si;
            n >>= 1;
        }
    }

    float hre = hr[(size_t)b * D + d];
    float him = hi[(size_t)b * D + d];

    const float* xp = x + ((size_t)b * L + (size_t)c * LC) * D + d;
    float* outr = out + ((size_t)b * L + (size_t)c * LC) * D + d;
    float* outr2 = outr + BLD;                                  // MODE 0 second plane
    float* outc = out + BLD + (((size_t)b * L + (size_t)c * LC) * D + d) * 2;

#pragma unroll 4
    for (int i = 0; i < LC; ++i) {
        float xv = xp[(size_t)i * D];
        float nr = fmaf(ph.x, ur, fmaf(-ph.y, ui, xv));
        float ni = fmaf(ph.x, ui, ph.y * ur);
        ur = nr;
        ui = ni;
        // val = pi*u + hidden*pw
        float vr = fmaf(q.x, ur, fmaf(-q.y, ui, fmaf(hre, pwr, -him * pwi)));
        float vi = fmaf(q.x, ui, fmaf(q.y, ur, fmaf(hre, pwi, him * pwr)));
        __builtin_nontemporal_store(vr, outr + (size_t)i * D);
        if (MODE == 0) {
            __builtin_nontemporal_store(vr, outr2 + (size_t)i * D);
        } else {
            v2f vc; vc.x = vr; vc.y = vi;
            __builtin_nontemporal_store(vc, (v2f*)(outc + (size_t)i * D * 2));
        }
        // pw *= phazor
        float tr = fmaf(pwr, ph.x, -pwi * ph.y);
        float ti = fmaf(pwr, ph.y, pwi * ph.x);
        pwr = tr;
        pwi = ti;
    }
}

// Fallback (no scratch needed): one thread per (b,d), full-L scan. Used only
// if ws_size is too small for the fast path.
template <int MODE>
__global__ __launch_bounds__(256) void fallback_k(const float* __restrict__ x,
                                                  const float* __restrict__ hr,
                                                  const float* __restrict__ hi,
                                                  const float* __restrict__ pinit,
                                                  const float* __restrict__ pparam,
                                                  float* __restrict__ out) {
    int idx = blockIdx.x * blockDim.x + threadIdx.x;   // b*D + d
    if (idx >= B * D) return;
    int d = idx % D;
    int b = idx / D;
    v2f ph = phazor_of(pparam, d);
    float qr = pinit[d * 2 + 0];
    float qi = pinit[d * 2 + 1];
    float hre = hr[(size_t)b * D + d];
    float him = hi[(size_t)b * D + d];
    float ur = 0.f, ui = 0.f;
    float pwr = ph.x, pwi = ph.y;                  // phazor^(t+1), t=0
    const float* xp = x + (size_t)b * L * D + d;
    float* outr = out + (size_t)b * L * D + d;
    float* outr2 = outr + BLD;
    float* outc = out + BLD + ((size_t)b * L * D + d) * 2;
    for (int t = 0; t < L; ++t) {
        float xv = xp[(size_t)t * D];
        float nr = fmaf(ph.x, ur, fmaf(-ph.y, ui, xv));
        float ni = fmaf(ph.x, ui, ph.y * ur);
        ur = nr; ui = ni;
        float vr = fmaf(qr, ur, fmaf(-qi, ui, fmaf(hre, pwr, -him * pwi)));
        float vi = fmaf(qr, ui, fmaf(qi, ur, fmaf(hre, pwi, him * pwr)));
        outr[(size_t)t * D] = vr;
        if (MODE == 0) {
            outr2[(size_t)t * D] = vr;
        } else {
            v2f vc; vc.x = vr; vc.y = vi;
            *(v2f*)(outc + (size_t)t * D * 2) = vc;
        }
        float tr = fmaf(pwr, ph.x, -pwi * ph.y);
        float ti = fmaf(pwr, ph.y, pwi * ph.x);
        pwr = tr; pwi = ti;
    }
}

extern "C" void kernel_launch(void* const* d_in, const int* in_sizes, int n_in,
                              void* d_out, int out_size, void* d_ws, size_t ws_size,
                              hipStream_t stream) {
    const float* x = (const float*)d_in[0];
    const float* hreal = (const float*)d_in[1];
    const float* himag = (const float*)d_in[2];
    const float* pinit = (const float*)d_in[3];
    const float* pparam = (const float*)d_in[4];
    float* le = (float*)d_ws;
    float* out = (float*)d_out;

    const int mode = (out_size >= (int)(3 * BLD)) ? 1 : 0;
    const bool fast = ws_size >= (size_t)WS_FLOATS * sizeof(float);

    if (fast) {
        int n = B * CK * D;                       // 262144 threads -> 4 waves/SIMD
        pass1_k<<<n / 256, 256, 0, stream>>>(x, pparam, le);
        if (mode == 0)
            pass2_k<0><<<n / 256, 256, 0, stream>>>(x, hreal, himag, pinit, pparam, le, out);
        else
            pass2_k<1><<<n / 256, 256, 0, stream>>>(x, hreal, himag, pinit, pparam, le, out);
    } else {
        int n = B * D;                            // 4096 threads
        if (mode == 0)
            fallback_k<0><<<(n + 255) / 256, 256, 0, stream>>>(x, hreal, himag, pinit, pparam, out);
        else
            fallback_k<1><<<(n + 255) / 256, 256, 0, stream>>>(x, hreal, himag, pinit, pparam, out);
    }
}

// Round 13
// 50.668 us; speedup vs baseline: 22.8257x; 1.0284x over previous
//
#include <hip/hip_runtime.h>
#include <math.h>

// Problem constants (from reference): x[B][L][D] fp32
#define B 8
#define L 4096
#define D 512
#define LC 64               // chunk length
#define CK (L / LC)         // 64 chunks
#define BLD ((size_t)B * L * D)

typedef float v2f __attribute__((ext_vector_type(2)));

// ws layout (floats): le [B][CK][D][2]  (chunk-local scan end states)
#define WS_FLOATS (2 * B * CK * D)           // 2 MiB

// phazor = exp(-|z|^2) * z/|z|   (no trig needed)
__device__ __forceinline__ v2f phazor_of(const float* __restrict__ pparam, int d) {
    float a = pparam[d * 2 + 0];
    float bb = pparam[d * 2 + 1];
    float r2 = fmaf(a, a, bb * bb);
    float inv = rsqrtf(r2);
    inv = inv * fmaf(-0.5f * r2 * inv, inv, 1.5f);   // Newton refinement
    float mag = __expf(-r2);
    v2f p; p.x = mag * a * inv; p.y = mag * bb * inv;
    return p;
}

// Pass 1: chunk-local scan with zero carry-in; store final state per (b,c,d).
__global__ __launch_bounds__(256) void pass1_k(const float* __restrict__ x,
                                               const float* __restrict__ pparam,
                                               float* __restrict__ le) {
    int idx = blockIdx.x * blockDim.x + threadIdx.x;   // b*CK*D + c*D + d
    int d = idx % D;
    int c = (idx / D) % CK;
    int b = idx / (D * CK);
    v2f ph = phazor_of(pparam, d);
    float ur = 0.f, ui = 0.f;
    const float* xp = x + ((size_t)b * L + (size_t)c * LC) * D + d;
#pragma unroll 8
    for (int i = 0; i < LC; ++i) {
        float xv = xp[(size_t)i * D];
        float nr = fmaf(ph.x, ur, fmaf(-ph.y, ui, xv));
        float ni = fmaf(ph.x, ui, ph.y * ur);
        ur = nr;
        ui = ni;
    }
    v2f lv; lv.x = ur; lv.y = ui;
    *(v2f*)(le + (size_t)idx * 2) = lv;
}

// Pass 2: rebuild carry-in by Horner over previous chunk ends (only needs
// P64 = phazor^LC), re-scan the chunk, write outputs nontemporally.
// MODE 0: out = [real plane][real plane]   (harness cast complex64 -> float32)
// MODE 1: out = [real plane][interleaved (re,im) plane]
template <int MODE>
__global__ __launch_bounds__(256) void pass2_k(const float* __restrict__ x,
                                               const float* __restrict__ hr,
                                               const float* __restrict__ hi,
                                               const float* __restrict__ pinit,
                                               const float* __restrict__ pparam,
                                               const float* __restrict__ le,
                                               float* __restrict__ out) {
    int idx = blockIdx.x * blockDim.x + threadIdx.x;   // b*CK*D + c*D + d
    int d = idx % D;
    int c = (idx / D) % CK;       // uniform within a block
    int b = idx / (D * CK);

    v2f ph = phazor_of(pparam, d);
    v2f q;  q.x = pinit[d * 2 + 0]; q.y = pinit[d * 2 + 1];

    // P64 = phazor^LC via 6 complex squarings
    float br = ph.x, bi = ph.y;
#pragma unroll
    for (int s = 0; s < 6; ++s) {
        float sr = fmaf(br, br, -bi * bi);
        float si = 2.f * br * bi;
        br = sr; bi = si;
    }

    // carry-in W[c] = sum_{j<c} P64^{c-1-j} * le[b][j][d]  (Horner, ascending j)
    float ur = 0.f, ui = 0.f;
    const float* lp = le + (((size_t)b * CK) * D + d) * 2;
    for (int j = 0; j < c; ++j) {
        v2f lv = *(const v2f*)(lp + (size_t)j * D * 2);
        float wr = fmaf(ur, br, fmaf(-ui, bi, lv.x));
        float wi = fmaf(ur, bi, fmaf(ui, br, lv.y));
        ur = wr; ui = wi;
    }

    // pw = phazor^(c*LC + 1) = P64^c * phazor  (binary exp over 6 bits of c)
    float pwr = ph.x, pwi = ph.y;
    {
        float er = br, ei = bi;
        int n = c;
#pragma unroll
        for (int s = 0; s < 6; ++s) {
            if (n & 1) {
                float tr = fmaf(pwr, er, -pwi * ei);
                float ti = fmaf(pwr, ei, pwi * er);
                pwr = tr; pwi = ti;
            }
            float sr = fmaf(er, er, -ei * ei);
            float si = 2.f * er * ei;
            er = sr; ei = si;
            n >>= 1;
        }
    }

    float hre = hr[(size_t)b * D + d];
    float him = hi[(size_t)b * D + d];

    const float* xp = x + ((size_t)b * L + (size_t)c * LC) * D + d;
    float* outr = out + ((size_t)b * L + (size_t)c * LC) * D + d;
    float* outr2 = outr + BLD;                                  // MODE 0 second plane
    float* outc = out + BLD + (((size_t)b * L + (size_t)c * LC) * D + d) * 2;

#pragma unroll 8
    for (int i = 0; i < LC; ++i) {
        float xv = xp[(size_t)i * D];
        float nr = fmaf(ph.x, ur, fmaf(-ph.y, ui, xv));
        float ni = fmaf(ph.x, ui, ph.y * ur);
        ur = nr;
        ui = ni;
        // val = pi*u + hidden*pw
        float vr = fmaf(q.x, ur, fmaf(-q.y, ui, fmaf(hre, pwr, -him * pwi)));
        float vi = fmaf(q.x, ui, fmaf(q.y, ur, fmaf(hre, pwi, him * pwr)));
        __builtin_nontemporal_store(vr, outr + (size_t)i * D);
        if (MODE == 0) {
            __builtin_nontemporal_store(vr, outr2 + (size_t)i * D);
        } else {
            v2f vc; vc.x = vr; vc.y = vi;
            __builtin_nontemporal_store(vc, (v2f*)(outc + (size_t)i * D * 2));
        }
        // pw *= phazor
        float tr = fmaf(pwr, ph.x, -pwi * ph.y);
        float ti = fmaf(pwr, ph.y, pwi * ph.x);
        pwr = tr;
        pwi = ti;
    }
}

// Fallback (no scratch needed): one thread per (b,d), full-L scan. Used only
// if ws_size is too small for the fast path.
template <int MODE>
__global__ __launch_bounds__(256) void fallback_k(const float* __restrict__ x,
                                                  const float* __restrict__ hr,
                                                  const float* __restrict__ hi,
                                                  const float* __restrict__ pinit,
                                                  const float* __restrict__ pparam,
                                                  float* __restrict__ out) {
    int idx = blockIdx.x * blockDim.x + threadIdx.x;   // b*D + d
    if (idx >= B * D) return;
    int d = idx % D;
    int b = idx / D;
    v2f ph = phazor_of(pparam, d);
    float qr = pinit[d * 2 + 0];
    float qi = pinit[d * 2 + 1];
    float hre = hr[(size_t)b * D + d];
    float him = hi[(size_t)b * D + d];
    float ur = 0.f, ui = 0.f;
    float pwr = ph.x, pwi = ph.y;                  // phazor^(t+1), t=0
    const float* xp = x + (size_t)b * L * D + d;
    float* outr = out + (size_t)b * L * D + d;
    float* outr2 = outr + BLD;
    float* outc = out + BLD + ((size_t)b * L * D + d) * 2;
    for (int t = 0; t < L; ++t) {
        float xv = xp[(size_t)t * D];
        float nr = fmaf(ph.x, ur, fmaf(-ph.y, ui, xv));
        float ni = fmaf(ph.x, ui, ph.y * ur);
        ur = nr; ui = ni;
        float vr = fmaf(qr, ur, fmaf(-qi, ui, fmaf(hre, pwr, -him * pwi)));
        float vi = fmaf(qr, ui, fmaf(qi, ur, fmaf(hre, pwi, him * pwr)));
        outr[(size_t)t * D] = vr;
        if (MODE == 0) {
            outr2[(size_t)t * D] = vr;
        } else {
            v2f vc; vc.x = vr; vc.y = vi;
            *(v2f*)(outc + (size_t)t * D * 2) = vc;
        }
        float tr = fmaf(pwr, ph.x, -pwi * ph.y);
        float ti = fmaf(pwr, ph.y, pwi * ph.x);
        pwr = tr; pwi = ti;
    }
}

extern "C" void kernel_launch(void* const* d_in, const int* in_sizes, int n_in,
                              void* d_out, int out_size, void* d_ws, size_t ws_size,
                              hipStream_t stream) {
    const float* x = (const float*)d_in[0];
    const float* hreal = (const float*)d_in[1];
    const float* himag = (const float*)d_in[2];
    const float* pinit = (const float*)d_in[3];
    const float* pparam = (const float*)d_in[4];
    float* le = (float*)d_ws;
    float* out = (float*)d_out;

    const int mode = (out_size >= (int)(3 * BLD)) ? 1 : 0;
    const bool fast = ws_size >= (size_t)WS_FLOATS * sizeof(float);

    if (fast) {
        int n = B * CK * D;                       // 262144 threads -> 4 waves/SIMD
        pass1_k<<<n / 256, 256, 0, stream>>>(x, pparam, le);
        if (mode == 0)
            pass2_k<0><<<n / 256, 256, 0, stream>>>(x, hreal, himag, pinit, pparam, le, out);
        else
            pass2_k<1><<<n / 256, 256, 0, stream>>>(x, hreal, himag, pinit, pparam, le, out);
    } else {
        int n = B * D;                            // 4096 threads
        if (mode == 0)
            fallback_k<0><<<(n + 255) / 256, 256, 0, stream>>>(x, hreal, himag, pinit, pparam, out);
        else
            fallback_k<1><<<(n + 255) / 256, 256, 0, stream>>>(x, hreal, himag, pinit, pparam, out);
    }
}